// Round 3
// baseline (551.378 us; speedup 1.0000x reference)
//
#include <hip/hip_runtime.h>

#define NB   32
#define DIMK 512
#define MM   32
#define ZZ   64
#define MZV  2048
#define VOC  50257

// ws layout in floats
#define WS_W      0                       // [NB][MZV] raw scores (incl. log mask)
#define WS_PVEC   (WS_W + NB*MZV)         // [NB][MM][DIMK] partial weighted vecs
#define WS_LSTAT  (WS_PVEC + NB*MM*DIMK)  // [NB][MM][2] (max, sum)
#define WS_GSTATW (WS_LSTAT + NB*MM*2)    // [NB][2] global (max,sum) copy branch
#define WS_MIX    (WS_GSTATW + NB*2)      // [NB][2]
#define WS_GPART  (WS_MIX + NB*2)         // [NB][32][2] gen softmax partials
#define WS_GSTATG (WS_GPART + NB*32*2)    // [NB][2]
#define WS_H      (WS_GSTATG + NB*2)      // [NB][1024] h = concat(encsumm, enc)

// K0: stage h = concat(encsumm, enc) contiguous for k4's uniform loads
__global__ void k0_stageh(const float* __restrict__ encsumm, const float* __restrict__ enc,
                          float* __restrict__ ws)
{
    int b = blockIdx.x;
    int c = threadIdx.x * 4;                       // 0..1020
    const float* src = (c < DIMK) ? (encsumm + b*DIMK + c) : (enc + b*DIMK + (c - DIMK));
    *(float4*)(ws + WS_H + b*1024 + c) = *(const float4*)src;
}

// K1: per (b,m) block — scores + online-softmax weighted sum, memencs read ONCE
__global__ __launch_bounds__(256) void k1_mem(
    const float* __restrict__ enc, const float* __restrict__ embsumm,
    const float* __restrict__ memencs, const float* __restrict__ memembsumm,
    const float* __restrict__ memmask, float* __restrict__ ws)
{
    int blk = blockIdx.x;
    int b = blk >> 5, m = blk & 31;
    int tid = threadIdx.x, wid = tid >> 6, lane = tid & 63;
    int c0 = lane * 4, c1 = c0 + 256;
    const float* encb = enc + b * DIMK;
    const float* embb = embsumm + b * DIMK;
    float4 qe0 = *(const float4*)(encb + c0);
    float4 qe1 = *(const float4*)(encb + c1);
    float4 qm0 = *(const float4*)(embb + c0);
    float4 qm1 = *(const float4*)(embb + c1);
    const float* meb = memencs    + (long)(b*MM + m) * ZZ * DIMK;
    const float* mmb = memembsumm + (long)(b*MM + m) * ZZ * DIMK;
    const float* mkb = memmask    + (long)(b*MM + m) * ZZ;
    float* w_ws = ws + WS_W + b*MZV + m*ZZ;

    float lmax = -3.0e38f, lsum = 0.f;
    float4 a0 = make_float4(0.f,0.f,0.f,0.f), a1 = make_float4(0.f,0.f,0.f,0.f);

    for (int z = wid; z < ZZ; z += 4) {
        const float* mer = meb + z*DIMK;
        const float* mmr = mmb + z*DIMK;
        float4 e0 = *(const float4*)(mer + c0);
        float4 e1 = *(const float4*)(mer + c1);
        float4 s0 = *(const float4*)(mmr + c0);
        float4 s1 = *(const float4*)(mmr + c1);
        float d = e0.x*qe0.x + e0.y*qe0.y + e0.z*qe0.z + e0.w*qe0.w
                + e1.x*qe1.x + e1.y*qe1.y + e1.z*qe1.z + e1.w*qe1.w
                + s0.x*qm0.x + s0.y*qm0.y + s0.z*qm0.z + s0.w*qm0.w
                + s1.x*qm1.x + s1.y*qm1.y + s1.z*qm1.z + s1.w*qm1.w;
        #pragma unroll
        for (int off = 32; off; off >>= 1) d += __shfl_xor(d, off);
        d += logf(mkb[z]);                 // mask=1 -> +0; mask=0 -> -inf
        if (lane == 0) w_ws[z] = d;
        float nm = fmaxf(lmax, d);
        float sc = __expf(lmax - nm);
        float e  = __expf(d - nm);
        lsum = lsum * sc + e;
        a0.x = a0.x*sc + e*e0.x; a0.y = a0.y*sc + e*e0.y;
        a0.z = a0.z*sc + e*e0.z; a0.w = a0.w*sc + e*e0.w;
        a1.x = a1.x*sc + e*e1.x; a1.y = a1.y*sc + e*e1.y;
        a1.z = a1.z*sc + e*e1.z; a1.w = a1.w*sc + e*e1.w;
        lmax = nm;
    }

    __shared__ float sacc[4][DIMK];
    __shared__ float sst[4][2];
    *(float4*)&sacc[wid][c0] = a0;
    *(float4*)&sacc[wid][c1] = a1;
    if (lane == 0) { sst[wid][0] = lmax; sst[wid][1] = lsum; }
    __syncthreads();
    float bm = fmaxf(fmaxf(sst[0][0], sst[1][0]), fmaxf(sst[2][0], sst[3][0]));
    float sc0 = __expf(sst[0][0]-bm), sc1 = __expf(sst[1][0]-bm);
    float sc2 = __expf(sst[2][0]-bm), sc3 = __expf(sst[3][0]-bm);
    float bs = sst[0][1]*sc0 + sst[1][1]*sc1 + sst[2][1]*sc2 + sst[3][1]*sc3;
    int d0 = tid * 2;
    float2 v0 = *(float2*)&sacc[0][d0];
    float2 v1 = *(float2*)&sacc[1][d0];
    float2 v2 = *(float2*)&sacc[2][d0];
    float2 v3 = *(float2*)&sacc[3][d0];
    float p0 = v0.x*sc0 + v1.x*sc1 + v2.x*sc2 + v3.x*sc3;
    float p1 = v0.y*sc0 + v1.y*sc1 + v2.y*sc2 + v3.y*sc3;
    float* pv = ws + WS_PVEC + (long)(b*MM+m)*DIMK + d0;
    pv[0] = p0; pv[1] = p1;
    if (tid == 0) { float* ls = ws + WS_LSTAT + (b*MM+m)*2; ls[0] = bm; ls[1] = bs; }
}

// K2: combine the 32 m-partials per b -> mem_enc_summ (output 1) + global (max,sum)
__global__ __launch_bounds__(256) void k2_comb(float* __restrict__ out, float* __restrict__ ws)
{
    int b = blockIdx.x, tid = threadIdx.x;
    const float* ls = ws + WS_LSTAT + b*MM*2;
    float gm = -3.0e38f;
    #pragma unroll
    for (int m = 0; m < MM; m++) gm = fmaxf(gm, ls[m*2]);
    float gs = 0.f;
    #pragma unroll
    for (int m = 0; m < MM; m++) gs += ls[m*2+1] * __expf(ls[m*2] - gm);
    if (tid == 0) { ws[WS_GSTATW + b*2] = gm; ws[WS_GSTATW + b*2 + 1] = gs; }
    float inv = 1.0f / gs;
    int d0 = tid * 2;
    float p0 = 0.f, p1 = 0.f;
    for (int m = 0; m < MM; m++) {
        float sc = __expf(ls[m*2] - gm);
        const float* pv = ws + WS_PVEC + (long)(b*MM+m)*DIMK + d0;
        p0 += pv[0]*sc; p1 += pv[1]*sc;
    }
    out[(long)NB*VOC + b*DIMK + d0]     = p0 * inv;
    out[(long)NB*VOC + b*DIMK + d0 + 1] = p1 * inv;
}

// K3: mixer gates
__global__ void k3_mix(const float* __restrict__ encsumm, const float* __restrict__ enc,
                       const float* __restrict__ W_mix, const float* __restrict__ b_mix,
                       float* __restrict__ ws)
{
    int b = blockIdx.x, l = threadIdx.x;
    float d0 = 0.f, d1 = 0.f;
    #pragma unroll
    for (int p = 0; p < 4; p++) {
        int cc = l*4 + p*256;
        float4 h4 = (cc < 512) ? *(const float4*)(encsumm + b*DIMK + cc)
                               : *(const float4*)(enc + b*DIMK + cc - 512);
        float4 w0 = *(const float4*)(W_mix + cc);
        float4 w1 = *(const float4*)(W_mix + 1024 + cc);
        d0 += h4.x*w0.x + h4.y*w0.y + h4.z*w0.z + h4.w*w0.w;
        d1 += h4.x*w1.x + h4.y*w1.y + h4.z*w1.z + h4.w*w1.w;
    }
    #pragma unroll
    for (int off = 32; off; off >>= 1) { d0 += __shfl_xor(d0, off); d1 += __shfl_xor(d1, off); }
    if (l == 0) {
        d0 += b_mix[0]; d1 += b_mix[1];
        float mx = fmaxf(d0, d1);
        float e0 = __expf(d0-mx), e1 = __expf(d1-mx);
        float s = e0 + e1;
        ws[WS_MIX + b*2] = e0/s; ws[WS_MIX + b*2 + 1] = e1/s;
    }
}

// K4 v3: block = 64 vocab rows x 32 batches. W staged through LDS:
//  - global loads dense (128B/thread contiguous), double-buffered, prefetch-early
//  - LDS granule-major transposed layout pos(g,r)=g*64+(r^2(g>>3)) -> both the
//    ds_write and the per-lane ds_read_b128 (fixed g, r=lane) sit on the bank floor
//  - compute: lane owns vocab row r=lane; h wave-uniform (readfirstlane base ->
//    s_load, SGPR FMA operand); stores coalesced. W read exactly once from HBM.
__global__ __launch_bounds__(256) void k4_gemm(
    const float* __restrict__ hws,
    const float* __restrict__ W_out, const float* __restrict__ b_out,
    const float* __restrict__ unk, float* __restrict__ logits)
{
    __shared__ float lds[2][32*64*4];     // 2 x 32KB
    int tid = threadIdx.x, wid = tid >> 6, lane = tid & 63;
    int v0 = blockIdx.x * 64;

    // staging map: thread owns 128B contiguous of one W row
    int sr = tid >> 2;                    // 0..63 tile row
    int sq = tid & 3;                     // quarter of the 128-float chunk
    long srow = min(v0 + sr, VOC - 1);
    const float* sbase = W_out + srow * 1024 + sq * 32;

    int b0 = __builtin_amdgcn_readfirstlane(wid * 8);
    const float* hb = hws + b0 * 1024;

    float4 st[8];
    float acc[8] = {0.f,0.f,0.f,0.f,0.f,0.f,0.f,0.f};

    // prologue: chunk 0
    #pragma unroll
    for (int j = 0; j < 8; ++j) st[j] = *(const float4*)(sbase + j*4);
    #pragma unroll
    for (int j = 0; j < 8; ++j) {
        int g = sq*8 + j;
        *(float4*)&lds[0][(g*64 + (sr ^ (sq<<1)))*4] = st[j];
    }

    for (int c = 0; c < 8; ++c) {
        if (c + 1 < 8) {
            const float* nb = sbase + (c+1)*128;
            #pragma unroll
            for (int j = 0; j < 8; ++j) st[j] = *(const float4*)(nb + j*4);
        }
        __syncthreads();                  // chunk c visible
        int kc = c * 128;
        const float* lb = lds[c & 1];
        #pragma unroll
        for (int g = 0; g < 32; ++g) {
            float4 w = *(const float4*)&lb[(g*64 + (lane ^ ((g>>3)<<1)))*4];
            #pragma unroll
            for (int i = 0; i < 8; ++i) {
                float4 h4 = *(const float4*)(hb + i*1024 + kc + g*4);
                acc[i] += w.x*h4.x + w.y*h4.y + w.z*h4.z + w.w*h4.w;
            }
        }
        if (c + 1 < 8) {
            __syncthreads();              // everyone done reading buf[c^1] (chunk c-1)
            float* nlds = lds[(c+1)&1];
            #pragma unroll
            for (int j = 0; j < 8; ++j) {
                int g = sq*8 + j;
                *(float4*)&nlds[(g*64 + (sr ^ (sq<<1)))*4] = st[j];
            }
        }
    }

    int v = v0 + lane;
    if (v < VOC) {
        float bias = b_out[v] + logf(unk[v]);
        #pragma unroll
        for (int i = 0; i < 8; ++i)
            logits[(long)(b0 + i)*VOC + v] = acc[i] + bias;
    }
}

// K5: gen softmax stats, 32 chunks per b
__global__ __launch_bounds__(256) void k5_gstat(const float* __restrict__ logits, float* __restrict__ ws)
{
    int chunk = blockIdx.x, b = blockIdx.y, tid = threadIdx.x;
    const int CH = (VOC + 31) / 32;
    int v0 = chunk * CH;
    int v1 = min(VOC, v0 + CH);
    float m = -3.0e38f, s = 0.f;
    for (int v = v0 + tid; v < v1; v += 256) {
        float x = logits[(long)b*VOC + v];
        float nm = fmaxf(m, x);
        s = s*__expf(m - nm) + __expf(x - nm);
        m = nm;
    }
    #pragma unroll
    for (int off = 32; off; off >>= 1) {
        float om = __shfl_xor(m, off), os = __shfl_xor(s, off);
        float nm = fmaxf(m, om);
        s = s*__expf(m - nm) + os*__expf(om - nm);
        m = nm;
    }
    __shared__ float sm[4], ssum[4];
    int wid = tid >> 6, lane = tid & 63;
    if (lane == 0) { sm[wid] = m; ssum[wid] = s; }
    __syncthreads();
    if (tid == 0) {
        float gm = fmaxf(fmaxf(sm[0], sm[1]), fmaxf(sm[2], sm[3]));
        float gs = ssum[0]*__expf(sm[0]-gm) + ssum[1]*__expf(sm[1]-gm)
                 + ssum[2]*__expf(sm[2]-gm) + ssum[3]*__expf(sm[3]-gm);
        ws[WS_GPART + (b*32 + chunk)*2]     = gm;
        ws[WS_GPART + (b*32 + chunk)*2 + 1] = gs;
    }
}

// K5b: merge 32 chunk partials per b
__global__ void k5b_merge(float* __restrict__ ws)
{
    int b = blockIdx.x, l = threadIdx.x;
    float m = -3.0e38f, s = 0.f;
    if (l < 32) { m = ws[WS_GPART + (b*32+l)*2]; s = ws[WS_GPART + (b*32+l)*2 + 1]; }
    #pragma unroll
    for (int off = 32; off; off >>= 1) {
        float om = __shfl_xor(m, off), os = __shfl_xor(s, off);
        float nm = fmaxf(m, om);
        s = s*__expf(m - nm) + os*__expf(om - nm);
        m = nm;
    }
    if (l == 0) { ws[WS_GSTATG + b*2] = m; ws[WS_GSTATG + b*2 + 1] = s; }
}

// K6: probs = mix0 * softmax(logits), in place in d_out
__global__ __launch_bounds__(256) void k6_final(float* __restrict__ probs, const float* __restrict__ ws)
{
    int v = blockIdx.x*256 + threadIdx.x;
    int b = blockIdx.y;
    if (v >= VOC) return;
    float gm = ws[WS_GSTATG + b*2], gs = ws[WS_GSTATG + b*2 + 1];
    float mix0 = ws[WS_MIX + b*2];
    long idx = (long)b*VOC + v;
    probs[idx] = mix0 * __expf(probs[idx] - gm) / gs;
}

// K7: copy-branch scatter: probs[b, tok] += mix1*alpha
__global__ __launch_bounds__(256) void k7_scatter(const int* __restrict__ memids,
                                                  const float* __restrict__ ws,
                                                  float* __restrict__ probs)
{
    int idx = blockIdx.x*256 + threadIdx.x;   // NB*MZV = 65536
    int b = idx >> 11, mz = idx & 2047;
    float gm = ws[WS_GSTATW + b*2], gs = ws[WS_GSTATW + b*2 + 1];
    float mix1 = ws[WS_MIX + b*2 + 1];
    float alpha = __expf(ws[WS_W + b*MZV + mz] - gm) / gs;
    int tok = memids[b*MZV + mz];
    atomicAdd(&probs[(long)b*VOC + tok], mix1 * alpha);
}

extern "C" void kernel_launch(void* const* d_in, const int* in_sizes, int n_in,
                              void* d_out, int out_size, void* d_ws, size_t ws_size,
                              hipStream_t stream)
{
    const float* enc        = (const float*)d_in[0];
    const float* encsumm    = (const float*)d_in[1];
    const float* embsumm    = (const float*)d_in[2];
    const float* memencs    = (const float*)d_in[3];
    // d_in[4] = memencsumm: provably unused (zeros in both concat middles)
    const float* memembsumm = (const float*)d_in[5];
    const float* memmask    = (const float*)d_in[6];
    const int*   memids     = (const int*)d_in[7];
    const float* W_out      = (const float*)d_in[8];
    const float* b_out      = (const float*)d_in[9];
    const float* W_mix      = (const float*)d_in[10];
    const float* b_mix      = (const float*)d_in[11];
    const float* unk        = (const float*)d_in[12];
    float* out = (float*)d_out;
    float* ws  = (float*)d_ws;

    hipLaunchKernelGGL(k0_stageh, dim3(NB), dim3(256), 0, stream, encsumm, enc, ws);
    hipLaunchKernelGGL(k1_mem, dim3(NB*MM), dim3(256), 0, stream,
                       enc, embsumm, memencs, memembsumm, memmask, ws);
    hipLaunchKernelGGL(k2_comb, dim3(NB), dim3(256), 0, stream, out, ws);
    hipLaunchKernelGGL(k3_mix, dim3(NB), dim3(64), 0, stream, encsumm, enc, W_mix, b_mix, ws);
    hipLaunchKernelGGL(k4_gemm, dim3((VOC + 63)/64), dim3(256), 0, stream,
                       ws + WS_H, W_out, b_out, unk, out);
    hipLaunchKernelGGL(k5_gstat, dim3(32, NB), dim3(256), 0, stream, out, ws);
    hipLaunchKernelGGL(k5b_merge, dim3(NB), dim3(64), 0, stream, ws);
    hipLaunchKernelGGL(k6_final, dim3((VOC + 255)/256, NB), dim3(256), 0, stream, out, ws);
    hipLaunchKernelGGL(k7_scatter, dim3(NB*MZV/256), dim3(256), 0, stream, memids, ws, out);
}

// Round 4
// 205.234 us; speedup vs baseline: 2.6866x; 2.6866x over previous
//
#include <hip/hip_runtime.h>

#define NB   32
#define DIMK 512
#define MM   32
#define ZZ   64
#define MZV  2048
#define VOC  50257

// ws layout in floats
#define WS_W      0                       // [NB][MZV] raw scores (incl. log mask)
#define WS_PVEC   (WS_W + NB*MZV)         // [NB][MM][DIMK] partial weighted vecs
#define WS_LSTAT  (WS_PVEC + NB*MM*DIMK)  // [NB][MM][2] (max, sum)
#define WS_GSTATW (WS_LSTAT + NB*MM*2)    // [NB][2] global (max,sum) copy branch
#define WS_MIX    (WS_GSTATW + NB*2)      // [NB][2]
#define WS_GPART  (WS_MIX + NB*2)         // [NB][32][2] gen softmax partials
#define WS_GSTATG (WS_GPART + NB*32*2)    // [NB][2]
#define WS_H      (WS_GSTATG + NB*2)      // [NB][1024] h = concat(encsumm, enc)

// K0: stage h = concat(encsumm, enc) contiguous for k4
__global__ void k0_stageh(const float* __restrict__ encsumm, const float* __restrict__ enc,
                          float* __restrict__ ws)
{
    int b = blockIdx.x;
    int c = threadIdx.x * 4;                       // 0..1020
    const float* src = (c < DIMK) ? (encsumm + b*DIMK + c) : (enc + b*DIMK + (c - DIMK));
    *(float4*)(ws + WS_H + b*1024 + c) = *(const float4*)src;
}

// K1: per (b,m) block — scores + online-softmax weighted sum, memencs read ONCE
__global__ __launch_bounds__(256) void k1_mem(
    const float* __restrict__ enc, const float* __restrict__ embsumm,
    const float* __restrict__ memencs, const float* __restrict__ memembsumm,
    const float* __restrict__ memmask, float* __restrict__ ws)
{
    int blk = blockIdx.x;
    int b = blk >> 5, m = blk & 31;
    int tid = threadIdx.x, wid = tid >> 6, lane = tid & 63;
    int c0 = lane * 4, c1 = c0 + 256;
    const float* encb = enc + b * DIMK;
    const float* embb = embsumm + b * DIMK;
    float4 qe0 = *(const float4*)(encb + c0);
    float4 qe1 = *(const float4*)(encb + c1);
    float4 qm0 = *(const float4*)(embb + c0);
    float4 qm1 = *(const float4*)(embb + c1);
    const float* meb = memencs    + (long)(b*MM + m) * ZZ * DIMK;
    const float* mmb = memembsumm + (long)(b*MM + m) * ZZ * DIMK;
    const float* mkb = memmask    + (long)(b*MM + m) * ZZ;
    float* w_ws = ws + WS_W + b*MZV + m*ZZ;

    float lmax = -3.0e38f, lsum = 0.f;
    float4 a0 = make_float4(0.f,0.f,0.f,0.f), a1 = make_float4(0.f,0.f,0.f,0.f);

    for (int z = wid; z < ZZ; z += 4) {
        const float* mer = meb + z*DIMK;
        const float* mmr = mmb + z*DIMK;
        float4 e0 = *(const float4*)(mer + c0);
        float4 e1 = *(const float4*)(mer + c1);
        float4 s0 = *(const float4*)(mmr + c0);
        float4 s1 = *(const float4*)(mmr + c1);
        float d = e0.x*qe0.x + e0.y*qe0.y + e0.z*qe0.z + e0.w*qe0.w
                + e1.x*qe1.x + e1.y*qe1.y + e1.z*qe1.z + e1.w*qe1.w
                + s0.x*qm0.x + s0.y*qm0.y + s0.z*qm0.z + s0.w*qm0.w
                + s1.x*qm1.x + s1.y*qm1.y + s1.z*qm1.z + s1.w*qm1.w;
        #pragma unroll
        for (int off = 32; off; off >>= 1) d += __shfl_xor(d, off);
        d += logf(mkb[z]);                 // mask=1 -> +0; mask=0 -> -inf
        if (lane == 0) w_ws[z] = d;
        float nm = fmaxf(lmax, d);
        float sc = __expf(lmax - nm);
        float e  = __expf(d - nm);
        lsum = lsum * sc + e;
        a0.x = a0.x*sc + e*e0.x; a0.y = a0.y*sc + e*e0.y;
        a0.z = a0.z*sc + e*e0.z; a0.w = a0.w*sc + e*e0.w;
        a1.x = a1.x*sc + e*e1.x; a1.y = a1.y*sc + e*e1.y;
        a1.z = a1.z*sc + e*e1.z; a1.w = a1.w*sc + e*e1.w;
        lmax = nm;
    }

    __shared__ float sacc[4][DIMK];
    __shared__ float sst[4][2];
    *(float4*)&sacc[wid][c0] = a0;
    *(float4*)&sacc[wid][c1] = a1;
    if (lane == 0) { sst[wid][0] = lmax; sst[wid][1] = lsum; }
    __syncthreads();
    float bm = fmaxf(fmaxf(sst[0][0], sst[1][0]), fmaxf(sst[2][0], sst[3][0]));
    float sc0 = __expf(sst[0][0]-bm), sc1 = __expf(sst[1][0]-bm);
    float sc2 = __expf(sst[2][0]-bm), sc3 = __expf(sst[3][0]-bm);
    float bs = sst[0][1]*sc0 + sst[1][1]*sc1 + sst[2][1]*sc2 + sst[3][1]*sc3;
    int d0 = tid * 2;
    float2 v0 = *(float2*)&sacc[0][d0];
    float2 v1 = *(float2*)&sacc[1][d0];
    float2 v2 = *(float2*)&sacc[2][d0];
    float2 v3 = *(float2*)&sacc[3][d0];
    float p0 = v0.x*sc0 + v1.x*sc1 + v2.x*sc2 + v3.x*sc3;
    float p1 = v0.y*sc0 + v1.y*sc1 + v2.y*sc2 + v3.y*sc3;
    float* pv = ws + WS_PVEC + (long)(b*MM+m)*DIMK + d0;
    pv[0] = p0; pv[1] = p1;
    if (tid == 0) { float* ls = ws + WS_LSTAT + (b*MM+m)*2; ls[0] = bm; ls[1] = bs; }
}

// K2: combine the 32 m-partials per b -> mem_enc_summ (output 1) + global (max,sum)
__global__ __launch_bounds__(256) void k2_comb(float* __restrict__ out, float* __restrict__ ws)
{
    int b = blockIdx.x, tid = threadIdx.x;
    const float* ls = ws + WS_LSTAT + b*MM*2;
    float gm = -3.0e38f;
    #pragma unroll
    for (int m = 0; m < MM; m++) gm = fmaxf(gm, ls[m*2]);
    float gs = 0.f;
    #pragma unroll
    for (int m = 0; m < MM; m++) gs += ls[m*2+1] * __expf(ls[m*2] - gm);
    if (tid == 0) { ws[WS_GSTATW + b*2] = gm; ws[WS_GSTATW + b*2 + 1] = gs; }
    float inv = 1.0f / gs;
    int d0 = tid * 2;
    float p0 = 0.f, p1 = 0.f;
    for (int m = 0; m < MM; m++) {
        float sc = __expf(ls[m*2] - gm);
        const float* pv = ws + WS_PVEC + (long)(b*MM+m)*DIMK + d0;
        p0 += pv[0]*sc; p1 += pv[1]*sc;
    }
    out[(long)NB*VOC + b*DIMK + d0]     = p0 * inv;
    out[(long)NB*VOC + b*DIMK + d0 + 1] = p1 * inv;
}

// K3: mixer gates
__global__ void k3_mix(const float* __restrict__ encsumm, const float* __restrict__ enc,
                       const float* __restrict__ W_mix, const float* __restrict__ b_mix,
                       float* __restrict__ ws)
{
    int b = blockIdx.x, l = threadIdx.x;
    float d0 = 0.f, d1 = 0.f;
    #pragma unroll
    for (int p = 0; p < 4; p++) {
        int cc = l*4 + p*256;
        float4 h4 = (cc < 512) ? *(const float4*)(encsumm + b*DIMK + cc)
                               : *(const float4*)(enc + b*DIMK + cc - 512);
        float4 w0 = *(const float4*)(W_mix + cc);
        float4 w1 = *(const float4*)(W_mix + 1024 + cc);
        d0 += h4.x*w0.x + h4.y*w0.y + h4.z*w0.z + h4.w*w0.w;
        d1 += h4.x*w1.x + h4.y*w1.y + h4.z*w1.z + h4.w*w1.w;
    }
    #pragma unroll
    for (int off = 32; off; off >>= 1) { d0 += __shfl_xor(d0, off); d1 += __shfl_xor(d1, off); }
    if (l == 0) {
        d0 += b_mix[0]; d1 += b_mix[1];
        float mx = fmaxf(d0, d1);
        float e0 = __expf(d0-mx), e1 = __expf(d1-mx);
        float s = e0 + e1;
        ws[WS_MIX + b*2] = e0/s; ws[WS_MIX + b*2 + 1] = e1/s;
    }
}

// K4 v4: Round-1 structure, spill-free. 512 threads = 8 waves; wave owns 4
// batches (h[4][4] = 64 VGPRs). All waves iterate the same 64-v tile: W row
// loads are DENSE 1KB/instr (lane spans K), 7/8 waves hit L1. Bisection-pack
// reduce (4 sums in ~25 instrs). Results staged in LDS, written out as
// coalesced float4 rows; bias (b_out + log unk) computed once per v.
__global__ __launch_bounds__(512) void k4_gemm(
    const float* __restrict__ hws,
    const float* __restrict__ W_out, const float* __restrict__ b_out,
    const float* __restrict__ unk, float* __restrict__ logits)
{
    __shared__ float lds_out[32*68];      // 68-float rows: 16B-aligned, bank-spread
    __shared__ float bias_lds[64];
    int tid = threadIdx.x, wid = tid >> 6, lane = tid & 63;
    int b0 = wid * 4;
    int c = lane * 4;
    int vt = blockIdx.x * 64;

    float4 h[4][4];
    #pragma unroll
    for (int i = 0; i < 4; ++i)
        #pragma unroll
        for (int p = 0; p < 4; ++p)
            h[i][p] = *(const float4*)(hws + (b0 + i)*1024 + c + p*256);

    for (int vo = 0; vo < 64; ++vo) {
        int v = vt + vo;
        int vc = min(v, VOC - 1);
        const float* wr = W_out + (long)vc * 1024;
        float a0 = 0.f, a1 = 0.f, a2 = 0.f, a3 = 0.f;
        #pragma unroll
        for (int p = 0; p < 4; ++p) {
            float4 w = *(const float4*)(wr + c + p*256);
            a0 += w.x*h[0][p].x + w.y*h[0][p].y + w.z*h[0][p].z + w.w*h[0][p].w;
            a1 += w.x*h[1][p].x + w.y*h[1][p].y + w.z*h[1][p].z + w.w*h[1][p].w;
            a2 += w.x*h[2][p].x + w.y*h[2][p].y + w.z*h[2][p].z + w.w*h[2][p].w;
            a3 += w.x*h[3][p].x + w.y*h[3][p].y + w.z*h[3][p].z + w.w*h[3][p].w;
        }
        // bisection-pack reduce: 4 sums across 64 lanes
        bool hi5 = (lane & 32) != 0;
        float x0 = hi5 ? a2 : a0, y0 = hi5 ? a0 : a2;
        float x1 = hi5 ? a3 : a1, y1 = hi5 ? a1 : a3;
        x0 += __shfl_xor(y0, 32);
        x1 += __shfl_xor(y1, 32);
        bool hi4 = (lane & 16) != 0;
        float u = hi4 ? x1 : x0, y = hi4 ? x0 : x1;
        u += __shfl_xor(y, 16);
        u += __shfl_xor(u, 8);
        u += __shfl_xor(u, 4);
        u += __shfl_xor(u, 2);
        u += __shfl_xor(u, 1);
        // group g = lane>>4 holds batch b0+g sum (broadcast within group)
        if ((lane & 15) == 0)
            lds_out[(b0 + (lane >> 4))*68 + vo] = u;
    }
    if (tid < 64) {
        int vg = min(vt + tid, VOC - 1);
        bias_lds[tid] = b_out[vg] + logf(unk[vg]);
    }
    __syncthreads();
    int batch = tid >> 4, chunk = tid & 15;
    float4 r = *(float4*)&lds_out[batch*68 + chunk*4];
    float4 bb = *(float4*)&bias_lds[chunk*4];
    r.x += bb.x; r.y += bb.y; r.z += bb.z; r.w += bb.w;
    int vg = vt + chunk*4;
    float* dst = logits + (long)batch*VOC + vg;
    if (vg + 3 < VOC) {
        *(float4*)dst = r;
    } else {
        float rr[4] = {r.x, r.y, r.z, r.w};
        #pragma unroll
        for (int j = 0; j < 4; ++j)
            if (vg + j < VOC) dst[j] = rr[j];
    }
}

// K5: gen softmax stats, 32 chunks per b
__global__ __launch_bounds__(256) void k5_gstat(const float* __restrict__ logits, float* __restrict__ ws)
{
    int chunk = blockIdx.x, b = blockIdx.y, tid = threadIdx.x;
    const int CH = (VOC + 31) / 32;
    int v0 = chunk * CH;
    int v1 = min(VOC, v0 + CH);
    float m = -3.0e38f, s = 0.f;
    for (int v = v0 + tid; v < v1; v += 256) {
        float x = logits[(long)b*VOC + v];
        float nm = fmaxf(m, x);
        s = s*__expf(m - nm) + __expf(x - nm);
        m = nm;
    }
    #pragma unroll
    for (int off = 32; off; off >>= 1) {
        float om = __shfl_xor(m, off), os = __shfl_xor(s, off);
        float nm = fmaxf(m, om);
        s = s*__expf(m - nm) + os*__expf(om - nm);
        m = nm;
    }
    __shared__ float sm[4], ssum[4];
    int wid = tid >> 6, lane = tid & 63;
    if (lane == 0) { sm[wid] = m; ssum[wid] = s; }
    __syncthreads();
    if (tid == 0) {
        float gm = fmaxf(fmaxf(sm[0], sm[1]), fmaxf(sm[2], sm[3]));
        float gs = ssum[0]*__expf(sm[0]-gm) + ssum[1]*__expf(sm[1]-gm)
                 + ssum[2]*__expf(sm[2]-gm) + ssum[3]*__expf(sm[3]-gm);
        ws[WS_GPART + (b*32 + chunk)*2]     = gm;
        ws[WS_GPART + (b*32 + chunk)*2 + 1] = gs;
    }
}

// K5b: merge 32 chunk partials per b
__global__ void k5b_merge(float* __restrict__ ws)
{
    int b = blockIdx.x, l = threadIdx.x;
    float m = -3.0e38f, s = 0.f;
    if (l < 32) { m = ws[WS_GPART + (b*32+l)*2]; s = ws[WS_GPART + (b*32+l)*2 + 1]; }
    #pragma unroll
    for (int off = 32; off; off >>= 1) {
        float om = __shfl_xor(m, off), os = __shfl_xor(s, off);
        float nm = fmaxf(m, om);
        s = s*__expf(m - nm) + os*__expf(om - nm);
        m = nm;
    }
    if (l == 0) { ws[WS_GSTATG + b*2] = m; ws[WS_GSTATG + b*2 + 1] = s; }
}

// K6: probs = mix0 * softmax(logits), in place in d_out
__global__ __launch_bounds__(256) void k6_final(float* __restrict__ probs, const float* __restrict__ ws)
{
    int v = blockIdx.x*256 + threadIdx.x;
    int b = blockIdx.y;
    if (v >= VOC) return;
    float gm = ws[WS_GSTATG + b*2], gs = ws[WS_GSTATG + b*2 + 1];
    float mix0 = ws[WS_MIX + b*2];
    long idx = (long)b*VOC + v;
    probs[idx] = mix0 * __expf(probs[idx] - gm) / gs;
}

// K7: copy-branch scatter: probs[b, tok] += mix1*alpha
__global__ __launch_bounds__(256) void k7_scatter(const int* __restrict__ memids,
                                                  const float* __restrict__ ws,
                                                  float* __restrict__ probs)
{
    int idx = blockIdx.x*256 + threadIdx.x;   // NB*MZV = 65536
    int b = idx >> 11, mz = idx & 2047;
    float gm = ws[WS_GSTATW + b*2], gs = ws[WS_GSTATW + b*2 + 1];
    float mix1 = ws[WS_MIX + b*2 + 1];
    float alpha = __expf(ws[WS_W + b*MZV + mz] - gm) / gs;
    int tok = memids[b*MZV + mz];
    atomicAdd(&probs[(long)b*VOC + tok], mix1 * alpha);
}

extern "C" void kernel_launch(void* const* d_in, const int* in_sizes, int n_in,
                              void* d_out, int out_size, void* d_ws, size_t ws_size,
                              hipStream_t stream)
{
    const float* enc        = (const float*)d_in[0];
    const float* encsumm    = (const float*)d_in[1];
    const float* embsumm    = (const float*)d_in[2];
    const float* memencs    = (const float*)d_in[3];
    // d_in[4] = memencsumm: provably unused (zeros in both concat middles)
    const float* memembsumm = (const float*)d_in[5];
    const float* memmask    = (const float*)d_in[6];
    const int*   memids     = (const int*)d_in[7];
    const float* W_out      = (const float*)d_in[8];
    const float* b_out      = (const float*)d_in[9];
    const float* W_mix      = (const float*)d_in[10];
    const float* b_mix      = (const float*)d_in[11];
    const float* unk        = (const float*)d_in[12];
    float* out = (float*)d_out;
    float* ws  = (float*)d_ws;

    hipLaunchKernelGGL(k0_stageh, dim3(NB), dim3(256), 0, stream, encsumm, enc, ws);
    hipLaunchKernelGGL(k1_mem, dim3(NB*MM), dim3(256), 0, stream,
                       enc, embsumm, memencs, memembsumm, memmask, ws);
    hipLaunchKernelGGL(k2_comb, dim3(NB), dim3(256), 0, stream, out, ws);
    hipLaunchKernelGGL(k3_mix, dim3(NB), dim3(64), 0, stream, encsumm, enc, W_mix, b_mix, ws);
    hipLaunchKernelGGL(k4_gemm, dim3((VOC + 63)/64), dim3(512), 0, stream,
                       ws + WS_H, W_out, b_out, unk, out);
    hipLaunchKernelGGL(k5_gstat, dim3(32, NB), dim3(256), 0, stream, out, ws);
    hipLaunchKernelGGL(k5b_merge, dim3(NB), dim3(64), 0, stream, ws);
    hipLaunchKernelGGL(k6_final, dim3((VOC + 255)/256, NB), dim3(256), 0, stream, out, ws);
    hipLaunchKernelGGL(k7_scatter, dim3(NB*MZV/256), dim3(256), 0, stream, memids, ws, out);
}

// Round 5
// 156.933 us; speedup vs baseline: 3.5135x; 1.3078x over previous
//
#include <hip/hip_runtime.h>

#define NB   32
#define DIMK 512
#define MM   32
#define ZZ   64
#define MZV  2048
#define VOC  50257

typedef __attribute__((ext_vector_type(8))) short  short8;   // 8 bf16 = 4 VGPR
typedef __attribute__((ext_vector_type(4))) float  f32x4;
typedef __attribute__((ext_vector_type(8))) unsigned short ushort8;

// ws layout in floats
#define WS_W      0                       // [NB][MZV] raw scores (incl. log mask)
#define WS_PVEC   (WS_W + NB*MZV)         // [NB][MM][DIMK] partial weighted vecs
#define WS_LSTAT  (WS_PVEC + NB*MM*DIMK)  // [NB][MM][2] (max, sum)
#define WS_GSTATW (WS_LSTAT + NB*MM*2)    // [NB][2] global (max,sum) copy branch
#define WS_MIX    (WS_GSTATW + NB*2)      // [NB][2]
#define WS_GPART  (WS_MIX + NB*2)         // [NB][32][2] gen softmax partials
#define WS_H      (WS_GPART + NB*32*2)    // [NB][1024] bf16 h (as ushort, 16K floats region)

__device__ __forceinline__ unsigned short f2bf(float f) {
    unsigned int u = __float_as_uint(f);
    u = (u + 0x7fffu + ((u >> 16) & 1u)) >> 16;      // RNE
    return (unsigned short)u;
}

// K0: h = concat(encsumm, enc) converted to bf16, contiguous per batch
__global__ void k0_stageh(const float* __restrict__ encsumm, const float* __restrict__ enc,
                          float* __restrict__ ws)
{
    int b = blockIdx.x;
    int c = threadIdx.x * 4;                       // 0..1020
    const float* src = (c < DIMK) ? (encsumm + b*DIMK + c) : (enc + b*DIMK + (c - DIMK));
    float4 v = *(const float4*)src;
    ushort4 o;
    o.x = f2bf(v.x); o.y = f2bf(v.y); o.z = f2bf(v.z); o.w = f2bf(v.w);
    *(ushort4*)((unsigned short*)(ws + WS_H) + b*1024 + c) = o;
}

// K1: per (b,m) block — scores + online-softmax weighted sum, memencs read ONCE
__global__ __launch_bounds__(256) void k1_mem(
    const float* __restrict__ enc, const float* __restrict__ embsumm,
    const float* __restrict__ memencs, const float* __restrict__ memembsumm,
    const float* __restrict__ memmask, float* __restrict__ ws)
{
    int blk = blockIdx.x;
    int b = blk >> 5, m = blk & 31;
    int tid = threadIdx.x, wid = tid >> 6, lane = tid & 63;
    int c0 = lane * 4, c1 = c0 + 256;
    const float* encb = enc + b * DIMK;
    const float* embb = embsumm + b * DIMK;
    float4 qe0 = *(const float4*)(encb + c0);
    float4 qe1 = *(const float4*)(encb + c1);
    float4 qm0 = *(const float4*)(embb + c0);
    float4 qm1 = *(const float4*)(embb + c1);
    const float* meb = memencs    + (long)(b*MM + m) * ZZ * DIMK;
    const float* mmb = memembsumm + (long)(b*MM + m) * ZZ * DIMK;
    const float* mkb = memmask    + (long)(b*MM + m) * ZZ;
    float* w_ws = ws + WS_W + b*MZV + m*ZZ;

    float lmax = -3.0e38f, lsum = 0.f;
    float4 a0 = make_float4(0.f,0.f,0.f,0.f), a1 = make_float4(0.f,0.f,0.f,0.f);

    for (int z = wid; z < ZZ; z += 4) {
        const float* mer = meb + z*DIMK;
        const float* mmr = mmb + z*DIMK;
        float4 e0 = *(const float4*)(mer + c0);
        float4 e1 = *(const float4*)(mer + c1);
        float4 s0 = *(const float4*)(mmr + c0);
        float4 s1 = *(const float4*)(mmr + c1);
        float d = e0.x*qe0.x + e0.y*qe0.y + e0.z*qe0.z + e0.w*qe0.w
                + e1.x*qe1.x + e1.y*qe1.y + e1.z*qe1.z + e1.w*qe1.w
                + s0.x*qm0.x + s0.y*qm0.y + s0.z*qm0.z + s0.w*qm0.w
                + s1.x*qm1.x + s1.y*qm1.y + s1.z*qm1.z + s1.w*qm1.w;
        #pragma unroll
        for (int off = 32; off; off >>= 1) d += __shfl_xor(d, off);
        d += logf(mkb[z]);                 // mask=1 -> +0; mask=0 -> -inf
        if (lane == 0) w_ws[z] = d;
        float nm = fmaxf(lmax, d);
        float sc = __expf(lmax - nm);
        float e  = __expf(d - nm);
        lsum = lsum * sc + e;
        a0.x = a0.x*sc + e*e0.x; a0.y = a0.y*sc + e*e0.y;
        a0.z = a0.z*sc + e*e0.z; a0.w = a0.w*sc + e*e0.w;
        a1.x = a1.x*sc + e*e1.x; a1.y = a1.y*sc + e*e1.y;
        a1.z = a1.z*sc + e*e1.z; a1.w = a1.w*sc + e*e1.w;
        lmax = nm;
    }

    __shared__ float sacc[4][DIMK];
    __shared__ float sst[4][2];
    *(float4*)&sacc[wid][c0] = a0;
    *(float4*)&sacc[wid][c1] = a1;
    if (lane == 0) { sst[wid][0] = lmax; sst[wid][1] = lsum; }
    __syncthreads();
    float bm = fmaxf(fmaxf(sst[0][0], sst[1][0]), fmaxf(sst[2][0], sst[3][0]));
    float sc0 = __expf(sst[0][0]-bm), sc1 = __expf(sst[1][0]-bm);
    float sc2 = __expf(sst[2][0]-bm), sc3 = __expf(sst[3][0]-bm);
    float bs = sst[0][1]*sc0 + sst[1][1]*sc1 + sst[2][1]*sc2 + sst[3][1]*sc3;
    int d0 = tid * 2;
    float2 v0 = *(float2*)&sacc[0][d0];
    float2 v1 = *(float2*)&sacc[1][d0];
    float2 v2 = *(float2*)&sacc[2][d0];
    float2 v3 = *(float2*)&sacc[3][d0];
    float p0 = v0.x*sc0 + v1.x*sc1 + v2.x*sc2 + v3.x*sc3;
    float p1 = v0.y*sc0 + v1.y*sc1 + v2.y*sc2 + v3.y*sc3;
    float* pv = ws + WS_PVEC + (long)(b*MM+m)*DIMK + d0;
    pv[0] = p0; pv[1] = p1;
    if (tid == 0) { float* ls = ws + WS_LSTAT + (b*MM+m)*2; ls[0] = bm; ls[1] = bs; }
}

// K2: combine the 32 m-partials per b -> mem_enc_summ (output 1) + global (max,sum)
__global__ __launch_bounds__(256) void k2_comb(float* __restrict__ out, float* __restrict__ ws)
{
    int b = blockIdx.x, tid = threadIdx.x;
    const float* ls = ws + WS_LSTAT + b*MM*2;
    float gm = -3.0e38f;
    #pragma unroll
    for (int m = 0; m < MM; m++) gm = fmaxf(gm, ls[m*2]);
    float gs = 0.f;
    #pragma unroll
    for (int m = 0; m < MM; m++) gs += ls[m*2+1] * __expf(ls[m*2] - gm);
    if (tid == 0) { ws[WS_GSTATW + b*2] = gm; ws[WS_GSTATW + b*2 + 1] = gs; }
    float inv = 1.0f / gs;
    int d0 = tid * 2;
    float p0 = 0.f, p1 = 0.f;
    for (int m = 0; m < MM; m++) {
        float sc = __expf(ls[m*2] - gm);
        const float* pv = ws + WS_PVEC + (long)(b*MM+m)*DIMK + d0;
        p0 += pv[0]*sc; p1 += pv[1]*sc;
    }
    out[(long)NB*VOC + b*DIMK + d0]     = p0 * inv;
    out[(long)NB*VOC + b*DIMK + d0 + 1] = p1 * inv;
}

// K3: mixer gates
__global__ void k3_mix(const float* __restrict__ encsumm, const float* __restrict__ enc,
                       const float* __restrict__ W_mix, const float* __restrict__ b_mix,
                       float* __restrict__ ws)
{
    int b = blockIdx.x, l = threadIdx.x;
    float d0 = 0.f, d1 = 0.f;
    #pragma unroll
    for (int p = 0; p < 4; p++) {
        int cc = l*4 + p*256;
        float4 h4 = (cc < 512) ? *(const float4*)(encsumm + b*DIMK + cc)
                               : *(const float4*)(enc + b*DIMK + cc - 512);
        float4 w0 = *(const float4*)(W_mix + cc);
        float4 w1 = *(const float4*)(W_mix + 1024 + cc);
        d0 += h4.x*w0.x + h4.y*w0.y + h4.z*w0.z + h4.w*w0.w;
        d1 += h4.x*w1.x + h4.y*w1.y + h4.z*w1.z + h4.w*w1.w;
    }
    #pragma unroll
    for (int off = 32; off; off >>= 1) { d0 += __shfl_xor(d0, off); d1 += __shfl_xor(d1, off); }
    if (l == 0) {
        d0 += b_mix[0]; d1 += b_mix[1];
        float mx = fmaxf(d0, d1);
        float e0 = __expf(d0-mx), e1 = __expf(d1-mx);
        float s = e0 + e1;
        ws[WS_MIX + b*2] = e0/s; ws[WS_MIX + b*2 + 1] = e1/s;
    }
}

// K4 v5 (MFMA): block = 64 v-cols x 32 batches, 4 waves (wave = 16 v, 2 M-tiles).
// W f32 loaded dense (128B/thread), converted to bf16 in-register, staged in LDS
// as B-fragment granules [s][ko][v][8]; every 16-lane group's ds op is 256B-dense.
// A-frags loaded from pre-converted h_bf16 (L2-resident, 64KB). C accum f32.
__global__ __launch_bounds__(256) void k4_gemm(
    const unsigned short* __restrict__ hbf,
    const float* __restrict__ W_out, const float* __restrict__ b_out,
    const float* __restrict__ unk, float* __restrict__ logits)
{
    __shared__ unsigned short b_lds[4*4*64*8];     // [s][ko][v][8] = 16 KB
    int tid = threadIdx.x, wid = tid >> 6, lane = tid & 63;
    int vt = blockIdx.x * 64;

    // staging map: thread owns 32 contiguous floats (128B) of one W row
    int r = tid >> 2;                    // local row 0..63
    int q = tid & 3;                     // k-quarter within 128-chunk (= s index)
    long grow = min(vt + r, VOC - 1);
    const float* wbase = W_out + grow * 1024 + q * 32;

    int lg = lane >> 4;                  // ko group
    int ln = lane & 15;
    const unsigned short* ha0 = hbf + ln * 1024;           // A rows 0..15
    const unsigned short* ha1 = hbf + (ln + 16) * 1024;    // A rows 16..31

    f32x4 acc0 = {0.f,0.f,0.f,0.f};
    f32x4 acc1 = {0.f,0.f,0.f,0.f};

    for (int c = 0; c < 8; ++c) {
        int kc = c * 128;
        // ---- stage chunk c: load 8x float4, cvt, pack, 4x ds_write_b128 ----
        const float* wp = wbase + kc;
        float4 f0 = *(const float4*)(wp +  0);
        float4 f1 = *(const float4*)(wp +  4);
        float4 f2 = *(const float4*)(wp +  8);
        float4 f3 = *(const float4*)(wp + 12);
        float4 f4 = *(const float4*)(wp + 16);
        float4 f5 = *(const float4*)(wp + 20);
        float4 f6 = *(const float4*)(wp + 24);
        float4 f7 = *(const float4*)(wp + 28);
        ushort8 g0, g1, g2, g3;
        g0[0]=f2bf(f0.x); g0[1]=f2bf(f0.y); g0[2]=f2bf(f0.z); g0[3]=f2bf(f0.w);
        g0[4]=f2bf(f1.x); g0[5]=f2bf(f1.y); g0[6]=f2bf(f1.z); g0[7]=f2bf(f1.w);
        g1[0]=f2bf(f2.x); g1[1]=f2bf(f2.y); g1[2]=f2bf(f2.z); g1[3]=f2bf(f2.w);
        g1[4]=f2bf(f3.x); g1[5]=f2bf(f3.y); g1[6]=f2bf(f3.z); g1[7]=f2bf(f3.w);
        g2[0]=f2bf(f4.x); g2[1]=f2bf(f4.y); g2[2]=f2bf(f4.z); g2[3]=f2bf(f4.w);
        g2[4]=f2bf(f5.x); g2[5]=f2bf(f5.y); g2[6]=f2bf(f5.z); g2[7]=f2bf(f5.w);
        g3[0]=f2bf(f6.x); g3[1]=f2bf(f6.y); g3[2]=f2bf(f6.z); g3[3]=f2bf(f6.w);
        g3[4]=f2bf(f7.x); g3[5]=f2bf(f7.y); g3[6]=f2bf(f7.z); g3[7]=f2bf(f7.w);
        *(ushort8*)&b_lds[((q*4 + 0)*64 + r)*8] = g0;
        *(ushort8*)&b_lds[((q*4 + 1)*64 + r)*8] = g1;
        *(ushort8*)&b_lds[((q*4 + 2)*64 + r)*8] = g2;
        *(ushort8*)&b_lds[((q*4 + 3)*64 + r)*8] = g3;
        __syncthreads();
        // ---- compute chunk c: 4 k-steps x 2 M-tiles ----
        #pragma unroll
        for (int s = 0; s < 4; ++s) {
            short8 bfrag = *(const short8*)&b_lds[((s*4 + lg)*64 + wid*16 + ln)*8];
            short8 a0 = *(const short8*)(ha0 + kc + s*32 + lg*8);
            short8 a1 = *(const short8*)(ha1 + kc + s*32 + lg*8);
            acc0 = __builtin_amdgcn_mfma_f32_16x16x32_bf16(a0, bfrag, acc0, 0, 0, 0);
            acc1 = __builtin_amdgcn_mfma_f32_16x16x32_bf16(a1, bfrag, acc1, 0, 0, 0);
        }
        __syncthreads();
    }

    // epilogue: C/D layout col=lane&15, row=(lane>>4)*4+reg  (m89-verified)
    int v = vt + wid*16 + ln;
    if (v < VOC) {
        float bias = b_out[v] + logf(unk[v]);
        #pragma unroll
        for (int rr = 0; rr < 4; ++rr) {
            int m = lg*4 + rr;
            logits[(long)m*VOC + v]        = acc0[rr] + bias;
            logits[(long)(m+16)*VOC + v]   = acc1[rr] + bias;
        }
    }
}

// K5: gen softmax stats, 32 chunks per b
__global__ __launch_bounds__(256) void k5_gstat(const float* __restrict__ logits, float* __restrict__ ws)
{
    int chunk = blockIdx.x, b = blockIdx.y, tid = threadIdx.x;
    const int CH = (VOC + 31) / 32;
    int v0 = chunk * CH;
    int v1 = min(VOC, v0 + CH);
    float m = -3.0e38f, s = 0.f;
    for (int v = v0 + tid; v < v1; v += 256) {
        float x = logits[(long)b*VOC + v];
        float nm = fmaxf(m, x);
        s = s*__expf(m - nm) + __expf(x - nm);
        m = nm;
    }
    #pragma unroll
    for (int off = 32; off; off >>= 1) {
        float om = __shfl_xor(m, off), os = __shfl_xor(s, off);
        float nm = fmaxf(m, om);
        s = s*__expf(m - nm) + os*__expf(om - nm);
        m = nm;
    }
    __shared__ float sm[4], ssum[4];
    int wid = tid >> 6, lane = tid & 63;
    if (lane == 0) { sm[wid] = m; ssum[wid] = s; }
    __syncthreads();
    if (tid == 0) {
        float gm = fmaxf(fmaxf(sm[0], sm[1]), fmaxf(sm[2], sm[3]));
        float gs = ssum[0]*__expf(sm[0]-gm) + ssum[1]*__expf(sm[1]-gm)
                 + ssum[2]*__expf(sm[2]-gm) + ssum[3]*__expf(sm[3]-gm);
        ws[WS_GPART + (b*32 + chunk)*2]     = gm;
        ws[WS_GPART + (b*32 + chunk)*2 + 1] = gs;
    }
}

// K6: probs = mix0 * softmax(logits), in place; merges the 32 chunk partials inline
__global__ __launch_bounds__(256) void k6_final(float* __restrict__ probs, const float* __restrict__ ws)
{
    int v = blockIdx.x*256 + threadIdx.x;
    int b = blockIdx.y;
    float gm = -3.0e38f;
    #pragma unroll
    for (int i = 0; i < 32; ++i) gm = fmaxf(gm, ws[WS_GPART + (b*32+i)*2]);
    float gs = 0.f;
    #pragma unroll
    for (int i = 0; i < 32; ++i)
        gs += ws[WS_GPART + (b*32+i)*2 + 1] * __expf(ws[WS_GPART + (b*32+i)*2] - gm);
    if (v >= VOC) return;
    float mix0 = ws[WS_MIX + b*2];
    long idx = (long)b*VOC + v;
    probs[idx] = mix0 * __expf(probs[idx] - gm) / gs;
}

// K7: copy-branch scatter: probs[b, tok] += mix1*alpha
__global__ __launch_bounds__(256) void k7_scatter(const int* __restrict__ memids,
                                                  const float* __restrict__ ws,
                                                  float* __restrict__ probs)
{
    int idx = blockIdx.x*256 + threadIdx.x;   // NB*MZV = 65536
    int b = idx >> 11, mz = idx & 2047;
    float gm = ws[WS_GSTATW + b*2], gs = ws[WS_GSTATW + b*2 + 1];
    float mix1 = ws[WS_MIX + b*2 + 1];
    float alpha = __expf(ws[WS_W + b*MZV + mz] - gm) / gs;
    int tok = memids[b*MZV + mz];
    atomicAdd(&probs[(long)b*VOC + tok], mix1 * alpha);
}

extern "C" void kernel_launch(void* const* d_in, const int* in_sizes, int n_in,
                              void* d_out, int out_size, void* d_ws, size_t ws_size,
                              hipStream_t stream)
{
    const float* enc        = (const float*)d_in[0];
    const float* encsumm    = (const float*)d_in[1];
    const float* embsumm    = (const float*)d_in[2];
    const float* memencs    = (const float*)d_in[3];
    // d_in[4] = memencsumm: provably unused (zeros in both concat middles)
    const float* memembsumm = (const float*)d_in[5];
    const float* memmask    = (const float*)d_in[6];
    const int*   memids     = (const int*)d_in[7];
    const float* W_out      = (const float*)d_in[8];
    const float* b_out      = (const float*)d_in[9];
    const float* W_mix      = (const float*)d_in[10];
    const float* b_mix      = (const float*)d_in[11];
    const float* unk        = (const float*)d_in[12];
    float* out = (float*)d_out;
    float* ws  = (float*)d_ws;

    hipLaunchKernelGGL(k0_stageh, dim3(NB), dim3(256), 0, stream, encsumm, enc, ws);
    hipLaunchKernelGGL(k1_mem, dim3(NB*MM), dim3(256), 0, stream,
                       enc, embsumm, memencs, memembsumm, memmask, ws);
    hipLaunchKernelGGL(k2_comb, dim3(NB), dim3(256), 0, stream, out, ws);
    hipLaunchKernelGGL(k3_mix, dim3(NB), dim3(64), 0, stream, encsumm, enc, W_mix, b_mix, ws);
    hipLaunchKernelGGL(k4_gemm, dim3((VOC + 63)/64), dim3(256), 0, stream,
                       (const unsigned short*)(ws + WS_H), W_out, b_out, unk, out);
    hipLaunchKernelGGL(k5_gstat, dim3(32, NB), dim3(256), 0, stream, out, ws);
    hipLaunchKernelGGL(k6_final, dim3((VOC + 255)/256, NB), dim3(256), 0, stream, out, ws);
    hipLaunchKernelGGL(k7_scatter, dim3(NB*MZV/256), dim3(256), 0, stream, memids, ws, out);
}

// Round 6
// 139.481 us; speedup vs baseline: 3.9531x; 1.1251x over previous
//
#include <hip/hip_runtime.h>
#include <hip/hip_bf16.h>

#define NB   32
#define DIMK 512
#define MM   32
#define ZZ   64
#define MZV  2048
#define VOC  50257

typedef __attribute__((ext_vector_type(8))) short  short8;   // 8 bf16 = 4 VGPR
typedef __attribute__((ext_vector_type(4))) float  f32x4;
typedef __attribute__((ext_vector_type(8))) unsigned short ushort8;

// ws layout in floats
#define WS_W      0                       // [NB][MZV] raw scores (incl. log mask)
#define WS_PVEC   (WS_W + NB*MZV)         // [NB][MM][DIMK] partial weighted vecs
#define WS_LSTAT  (WS_PVEC + NB*MM*DIMK)  // [NB][MM][2] (max, sum)
#define WS_GSTATW (WS_LSTAT + NB*MM*2)    // [NB][2] global (max,sum) copy branch
#define WS_MIX    (WS_GSTATW + NB*2)      // [NB][2]
#define WS_GPART  (WS_MIX + NB*2)         // [NB][32][2] gen softmax partials
#define WS_H      (WS_GPART + NB*32*2)    // [NB][1024] bf16 h (as ushort, 16K floats region)

// pack 8 f32 -> 8 bf16 (RNE) via v_cvt_pk_bf16_f32 (compiler-generated)
__device__ __forceinline__ ushort8 cvt8(float4 a, float4 b) {
    union { ushort8 u; __hip_bfloat162 h[4]; } r;
    r.h[0] = __float22bfloat162_rn(make_float2(a.x, a.y));
    r.h[1] = __float22bfloat162_rn(make_float2(a.z, a.w));
    r.h[2] = __float22bfloat162_rn(make_float2(b.x, b.y));
    r.h[3] = __float22bfloat162_rn(make_float2(b.z, b.w));
    return r.u;
}

// K0: h = concat(encsumm, enc) converted to bf16, contiguous per batch
__global__ void k0_stageh(const float* __restrict__ encsumm, const float* __restrict__ enc,
                          float* __restrict__ ws)
{
    int b = blockIdx.x;
    int c = threadIdx.x * 4;                       // 0..1020
    const float* src = (c < DIMK) ? (encsumm + b*DIMK + c) : (enc + b*DIMK + (c - DIMK));
    float4 v = *(const float4*)src;
    union { ushort4 u; __hip_bfloat162 h[2]; } o;
    o.h[0] = __float22bfloat162_rn(make_float2(v.x, v.y));
    o.h[1] = __float22bfloat162_rn(make_float2(v.z, v.w));
    *(ushort4*)((unsigned short*)(ws + WS_H) + b*1024 + c) = o.u;
}

// K1: per (b,m) block — scores + online-softmax weighted sum, memencs read ONCE
__global__ __launch_bounds__(256) void k1_mem(
    const float* __restrict__ enc, const float* __restrict__ embsumm,
    const float* __restrict__ memencs, const float* __restrict__ memembsumm,
    const float* __restrict__ memmask, float* __restrict__ ws)
{
    int blk = blockIdx.x;
    int b = blk >> 5, m = blk & 31;
    int tid = threadIdx.x, wid = tid >> 6, lane = tid & 63;
    int c0 = lane * 4, c1 = c0 + 256;
    const float* encb = enc + b * DIMK;
    const float* embb = embsumm + b * DIMK;
    float4 qe0 = *(const float4*)(encb + c0);
    float4 qe1 = *(const float4*)(encb + c1);
    float4 qm0 = *(const float4*)(embb + c0);
    float4 qm1 = *(const float4*)(embb + c1);
    const float* meb = memencs    + (long)(b*MM + m) * ZZ * DIMK;
    const float* mmb = memembsumm + (long)(b*MM + m) * ZZ * DIMK;
    const float* mkb = memmask    + (long)(b*MM + m) * ZZ;
    float* w_ws = ws + WS_W + b*MZV + m*ZZ;

    float lmax = -3.0e38f, lsum = 0.f;
    float4 a0 = make_float4(0.f,0.f,0.f,0.f), a1 = make_float4(0.f,0.f,0.f,0.f);

    for (int z = wid; z < ZZ; z += 4) {
        const float* mer = meb + z*DIMK;
        const float* mmr = mmb + z*DIMK;
        float4 e0 = *(const float4*)(mer + c0);
        float4 e1 = *(const float4*)(mer + c1);
        float4 s0 = *(const float4*)(mmr + c0);
        float4 s1 = *(const float4*)(mmr + c1);
        float d = e0.x*qe0.x + e0.y*qe0.y + e0.z*qe0.z + e0.w*qe0.w
                + e1.x*qe1.x + e1.y*qe1.y + e1.z*qe1.z + e1.w*qe1.w
                + s0.x*qm0.x + s0.y*qm0.y + s0.z*qm0.z + s0.w*qm0.w
                + s1.x*qm1.x + s1.y*qm1.y + s1.z*qm1.z + s1.w*qm1.w;
        #pragma unroll
        for (int off = 32; off; off >>= 1) d += __shfl_xor(d, off);
        d += logf(mkb[z]);                 // mask=1 -> +0; mask=0 -> -inf
        if (lane == 0) w_ws[z] = d;
        float nm = fmaxf(lmax, d);
        float sc = __expf(lmax - nm);
        float e  = __expf(d - nm);
        lsum = lsum * sc + e;
        a0.x = a0.x*sc + e*e0.x; a0.y = a0.y*sc + e*e0.y;
        a0.z = a0.z*sc + e*e0.z; a0.w = a0.w*sc + e*e0.w;
        a1.x = a1.x*sc + e*e1.x; a1.y = a1.y*sc + e*e1.y;
        a1.z = a1.z*sc + e*e1.z; a1.w = a1.w*sc + e*e1.w;
        lmax = nm;
    }

    __shared__ float sacc[4][DIMK];
    __shared__ float sst[4][2];
    *(float4*)&sacc[wid][c0] = a0;
    *(float4*)&sacc[wid][c1] = a1;
    if (lane == 0) { sst[wid][0] = lmax; sst[wid][1] = lsum; }
    __syncthreads();
    float bm = fmaxf(fmaxf(sst[0][0], sst[1][0]), fmaxf(sst[2][0], sst[3][0]));
    float sc0 = __expf(sst[0][0]-bm), sc1 = __expf(sst[1][0]-bm);
    float sc2 = __expf(sst[2][0]-bm), sc3 = __expf(sst[3][0]-bm);
    float bs = sst[0][1]*sc0 + sst[1][1]*sc1 + sst[2][1]*sc2 + sst[3][1]*sc3;
    int d0 = tid * 2;
    float2 v0 = *(float2*)&sacc[0][d0];
    float2 v1 = *(float2*)&sacc[1][d0];
    float2 v2 = *(float2*)&sacc[2][d0];
    float2 v3 = *(float2*)&sacc[3][d0];
    float p0 = v0.x*sc0 + v1.x*sc1 + v2.x*sc2 + v3.x*sc3;
    float p1 = v0.y*sc0 + v1.y*sc1 + v2.y*sc2 + v3.y*sc3;
    float* pv = ws + WS_PVEC + (long)(b*MM+m)*DIMK + d0;
    pv[0] = p0; pv[1] = p1;
    if (tid == 0) { float* ls = ws + WS_LSTAT + (b*MM+m)*2; ls[0] = bm; ls[1] = bs; }
}

// K2: combine the 32 m-partials per b -> mem_enc_summ (output 1) + global (max,sum)
__global__ __launch_bounds__(256) void k2_comb(float* __restrict__ out, float* __restrict__ ws)
{
    int b = blockIdx.x, tid = threadIdx.x;
    const float* ls = ws + WS_LSTAT + b*MM*2;
    float gm = -3.0e38f;
    #pragma unroll
    for (int m = 0; m < MM; m++) gm = fmaxf(gm, ls[m*2]);
    float gs = 0.f;
    #pragma unroll
    for (int m = 0; m < MM; m++) gs += ls[m*2+1] * __expf(ls[m*2] - gm);
    if (tid == 0) { ws[WS_GSTATW + b*2] = gm; ws[WS_GSTATW + b*2 + 1] = gs; }
    float inv = 1.0f / gs;
    int d0 = tid * 2;
    float p0 = 0.f, p1 = 0.f;
    for (int m = 0; m < MM; m++) {
        float sc = __expf(ls[m*2] - gm);
        const float* pv = ws + WS_PVEC + (long)(b*MM+m)*DIMK + d0;
        p0 += pv[0]*sc; p1 += pv[1]*sc;
    }
    out[(long)NB*VOC + b*DIMK + d0]     = p0 * inv;
    out[(long)NB*VOC + b*DIMK + d0 + 1] = p1 * inv;
}

// K3: mixer gates
__global__ void k3_mix(const float* __restrict__ encsumm, const float* __restrict__ enc,
                       const float* __restrict__ W_mix, const float* __restrict__ b_mix,
                       float* __restrict__ ws)
{
    int b = blockIdx.x, l = threadIdx.x;
    float d0 = 0.f, d1 = 0.f;
    #pragma unroll
    for (int p = 0; p < 4; p++) {
        int cc = l*4 + p*256;
        float4 h4 = (cc < 512) ? *(const float4*)(encsumm + b*DIMK + cc)
                               : *(const float4*)(enc + b*DIMK + cc - 512);
        float4 w0 = *(const float4*)(W_mix + cc);
        float4 w1 = *(const float4*)(W_mix + 1024 + cc);
        d0 += h4.x*w0.x + h4.y*w0.y + h4.z*w0.z + h4.w*w0.w;
        d1 += h4.x*w1.x + h4.y*w1.y + h4.z*w1.z + h4.w*w1.w;
    }
    #pragma unroll
    for (int off = 32; off; off >>= 1) { d0 += __shfl_xor(d0, off); d1 += __shfl_xor(d1, off); }
    if (l == 0) {
        d0 += b_mix[0]; d1 += b_mix[1];
        float mx = fmaxf(d0, d1);
        float e0 = __expf(d0-mx), e1 = __expf(d1-mx);
        float s = e0 + e1;
        ws[WS_MIX + b*2] = e0/s; ws[WS_MIX + b*2 + 1] = e1/s;
    }
}

// K4 v6 (MFMA): block = 64 v x 32 b, 4 waves. Per 128-k chunk:
//  - W: dense f32 loads (128B/thread), v_cvt_pk to bf16, staged to b_lds granules
//  - A (h): staged to a_lds (8 KB) with XOR-swizzled granule layout
//    pos = g*32 + (r ^ (g&7)); both ds_write and frag ds_read_b128 bank-spread.
//  - compute: 4 k-steps x (1 B-frag + 2 A-frag ds_read_b128 + 2 MFMA)
// LDS 24KB/block. No divergent global loads anywhere.
__global__ __launch_bounds__(256) void k4_gemm(
    const unsigned short* __restrict__ hbf,
    const float* __restrict__ W_out, const float* __restrict__ b_out,
    const float* __restrict__ unk, float* __restrict__ logits)
{
    __shared__ __align__(16) unsigned short b_lds[16*64*8];   // [g][v][8] = 16 KB
    __shared__ __align__(16) unsigned short a_lds[16*32*8];   // swizzled granules, 8 KB
    int tid = threadIdx.x, wid = tid >> 6, lane = tid & 63;
    int vt = blockIdx.x * 64;

    // W staging map: thread owns 32 contiguous floats (128B) of one W row
    int r = tid >> 2;                    // local row 0..63
    int q = tid & 3;                     // k-quarter within 128-chunk
    long grow = min(vt + r, VOC - 1);
    const float* wbase = W_out + grow * 1024 + q * 32;

    // A staging map: granule i = tid + 256j; row ar=i>>4 (0..31), gl ag=i&15
    int ar0 = tid >> 4, ag0 = tid & 15;          // j=0
    int ar1 = (tid + 256) >> 4, ag1 = ag0;       // j=1 (rows 16..31)

    int lg = lane >> 4;                  // k-group within step
    int ln = lane & 15;

    f32x4 acc0 = {0.f,0.f,0.f,0.f};
    f32x4 acc1 = {0.f,0.f,0.f,0.f};

    for (int c = 0; c < 8; ++c) {
        int kc = c * 128;
        // ---- stage A chunk: 2 x (16B load + swizzled ds_write) ----
        ushort8 av0 = *(const ushort8*)(hbf + ar0*1024 + kc + ag0*8);
        ushort8 av1 = *(const ushort8*)(hbf + ar1*1024 + kc + ag1*8);
        *(ushort8*)&a_lds[(ag0*32 + (ar0 ^ (ag0 & 7)))*8] = av0;
        *(ushort8*)&a_lds[(ag1*32 + (ar1 ^ (ag1 & 7)))*8] = av1;
        // ---- stage W chunk: 8x float4 load, cvt_pk, 4x ds_write_b128 ----
        const float* wp = wbase + kc;
        float4 f0 = *(const float4*)(wp +  0);
        float4 f1 = *(const float4*)(wp +  4);
        float4 f2 = *(const float4*)(wp +  8);
        float4 f3 = *(const float4*)(wp + 12);
        float4 f4 = *(const float4*)(wp + 16);
        float4 f5 = *(const float4*)(wp + 20);
        float4 f6 = *(const float4*)(wp + 24);
        float4 f7 = *(const float4*)(wp + 28);
        *(ushort8*)&b_lds[((q*4 + 0)*64 + r)*8] = cvt8(f0, f1);
        *(ushort8*)&b_lds[((q*4 + 1)*64 + r)*8] = cvt8(f2, f3);
        *(ushort8*)&b_lds[((q*4 + 2)*64 + r)*8] = cvt8(f4, f5);
        *(ushort8*)&b_lds[((q*4 + 3)*64 + r)*8] = cvt8(f6, f7);
        __syncthreads();
        // ---- compute chunk: 4 k-steps x 2 M-tiles ----
        #pragma unroll
        for (int s = 0; s < 4; ++s) {
            int g = s*4 + lg;
            short8 bfrag = *(const short8*)&b_lds[(g*64 + wid*16 + ln)*8];
            short8 a0 = *(const short8*)&a_lds[(g*32 + (ln ^ (g & 7)))*8];
            short8 a1 = *(const short8*)&a_lds[(g*32 + ((ln + 16) ^ (g & 7)))*8];
            acc0 = __builtin_amdgcn_mfma_f32_16x16x32_bf16(a0, bfrag, acc0, 0, 0, 0);
            acc1 = __builtin_amdgcn_mfma_f32_16x16x32_bf16(a1, bfrag, acc1, 0, 0, 0);
        }
        __syncthreads();
    }

    // epilogue: C/D layout col=lane&15, row=(lane>>4)*4+reg  (m89-verified)
    int v = vt + wid*16 + ln;
    if (v < VOC) {
        float bias = b_out[v] + logf(unk[v]);
        #pragma unroll
        for (int rr = 0; rr < 4; ++rr) {
            int m = lg*4 + rr;
            logits[(long)m*VOC + v]        = acc0[rr] + bias;
            logits[(long)(m+16)*VOC + v]   = acc1[rr] + bias;
        }
    }
}

// K5: gen softmax stats, 32 chunks per b
__global__ __launch_bounds__(256) void k5_gstat(const float* __restrict__ logits, float* __restrict__ ws)
{
    int chunk = blockIdx.x, b = blockIdx.y, tid = threadIdx.x;
    const int CH = (VOC + 31) / 32;
    int v0 = chunk * CH;
    int v1 = min(VOC, v0 + CH);
    float m = -3.0e38f, s = 0.f;
    for (int v = v0 + tid; v < v1; v += 256) {
        float x = logits[(long)b*VOC + v];
        float nm = fmaxf(m, x);
        s = s*__expf(m - nm) + __expf(x - nm);
        m = nm;
    }
    #pragma unroll
    for (int off = 32; off; off >>= 1) {
        float om = __shfl_xor(m, off), os = __shfl_xor(s, off);
        float nm = fmaxf(m, om);
        s = s*__expf(m - nm) + os*__expf(om - nm);
        m = nm;
    }
    __shared__ float sm[4], ssum[4];
    int wid = tid >> 6, lane = tid & 63;
    if (lane == 0) { sm[wid] = m; ssum[wid] = s; }
    __syncthreads();
    if (tid == 0) {
        float gm = fmaxf(fmaxf(sm[0], sm[1]), fmaxf(sm[2], sm[3]));
        float gs = ssum[0]*__expf(sm[0]-gm) + ssum[1]*__expf(sm[1]-gm)
                 + ssum[2]*__expf(sm[2]-gm) + ssum[3]*__expf(sm[3]-gm);
        ws[WS_GPART + (b*32 + chunk)*2]     = gm;
        ws[WS_GPART + (b*32 + chunk)*2 + 1] = gs;
    }
}

// K6: probs = mix0 * softmax(logits), in place; merges the 32 chunk partials inline
__global__ __launch_bounds__(256) void k6_final(float* __restrict__ probs, const float* __restrict__ ws)
{
    int v = blockIdx.x*256 + threadIdx.x;
    int b = blockIdx.y;
    float gm = -3.0e38f;
    #pragma unroll
    for (int i = 0; i < 32; ++i) gm = fmaxf(gm, ws[WS_GPART + (b*32+i)*2]);
    float gs = 0.f;
    #pragma unroll
    for (int i = 0; i < 32; ++i)
        gs += ws[WS_GPART + (b*32+i)*2 + 1] * __expf(ws[WS_GPART + (b*32+i)*2] - gm);
    if (v >= VOC) return;
    float mix0 = ws[WS_MIX + b*2];
    long idx = (long)b*VOC + v;
    probs[idx] = mix0 * __expf(probs[idx] - gm) / gs;
}

// K7: copy-branch scatter: probs[b, tok] += mix1*alpha
__global__ __launch_bounds__(256) void k7_scatter(const int* __restrict__ memids,
                                                  const float* __restrict__ ws,
                                                  float* __restrict__ probs)
{
    int idx = blockIdx.x*256 + threadIdx.x;   // NB*MZV = 65536
    int b = idx >> 11, mz = idx & 2047;
    float gm = ws[WS_GSTATW + b*2], gs = ws[WS_GSTATW + b*2 + 1];
    float mix1 = ws[WS_MIX + b*2 + 1];
    float alpha = __expf(ws[WS_W + b*MZV + mz] - gm) / gs;
    int tok = memids[b*MZV + mz];
    atomicAdd(&probs[(long)b*VOC + tok], mix1 * alpha);
}

extern "C" void kernel_launch(void* const* d_in, const int* in_sizes, int n_in,
                              void* d_out, int out_size, void* d_ws, size_t ws_size,
                              hipStream_t stream)
{
    const float* enc        = (const float*)d_in[0];
    const float* encsumm    = (const float*)d_in[1];
    const float* embsumm    = (const float*)d_in[2];
    const float* memencs    = (const float*)d_in[3];
    // d_in[4] = memencsumm: provably unused (zeros in both concat middles)
    const float* memembsumm = (const float*)d_in[5];
    const float* memmask    = (const float*)d_in[6];
    const int*   memids     = (const int*)d_in[7];
    const float* W_out      = (const float*)d_in[8];
    const float* b_out      = (const float*)d_in[9];
    const float* W_mix      = (const float*)d_in[10];
    const float* b_mix      = (const float*)d_in[11];
    const float* unk        = (const float*)d_in[12];
    float* out = (float*)d_out;
    float* ws  = (float*)d_ws;

    hipLaunchKernelGGL(k0_stageh, dim3(NB), dim3(256), 0, stream, encsumm, enc, ws);
    hipLaunchKernelGGL(k1_mem, dim3(NB*MM), dim3(256), 0, stream,
                       enc, embsumm, memencs, memembsumm, memmask, ws);
    hipLaunchKernelGGL(k2_comb, dim3(NB), dim3(256), 0, stream, out, ws);
    hipLaunchKernelGGL(k3_mix, dim3(NB), dim3(64), 0, stream, encsumm, enc, W_mix, b_mix, ws);
    hipLaunchKernelGGL(k4_gemm, dim3((VOC + 63)/64), dim3(256), 0, stream,
                       (const unsigned short*)(ws + WS_H), W_out, b_out, unk, out);
    hipLaunchKernelGGL(k5_gstat, dim3(32, NB), dim3(256), 0, stream, out, ws);
    hipLaunchKernelGGL(k6_final, dim3((VOC + 255)/256, NB), dim3(256), 0, stream, out, ws);
    hipLaunchKernelGGL(k7_scatter, dim3(NB*MZV/256), dim3(256), 0, stream, memids, ws, out);
}

// Round 7
// 138.097 us; speedup vs baseline: 3.9927x; 1.0100x over previous
//
#include <hip/hip_runtime.h>
#include <hip/hip_bf16.h>

#define NB   32
#define DIMK 512
#define MM   32
#define ZZ   64
#define MZV  2048
#define VOC  50257

typedef __attribute__((ext_vector_type(8))) short  short8;   // 8 bf16 = 4 VGPR
typedef __attribute__((ext_vector_type(4))) float  f32x4;
typedef __attribute__((ext_vector_type(8))) unsigned short ushort8;

// ws layout in floats
#define WS_W      0                       // [NB][MZV] raw scores (incl. log mask)
#define WS_PVEC   (WS_W + NB*MZV)         // [NB][MM][DIMK] partial weighted vecs
#define WS_LSTAT  (WS_PVEC + NB*MM*DIMK)  // [NB][MM][2] (max, sum)
#define WS_GSTATW (WS_LSTAT + NB*MM*2)    // [NB][2] global (max,sum) copy branch
#define WS_MIX    (WS_GSTATW + NB*2)      // [NB][2]
#define WS_GPART  (WS_MIX + NB*2)         // [NB][32][2] gen softmax partials
#define WS_H      (WS_GPART + NB*32*2)    // [NB][1024] bf16 h (as ushort)

// pack 8 f32 -> 8 bf16 (RNE) via v_cvt_pk_bf16_f32 (compiler-generated)
__device__ __forceinline__ ushort8 cvt8(float4 a, float4 b) {
    union { ushort8 u; __hip_bfloat162 h[4]; } r;
    r.h[0] = __float22bfloat162_rn(make_float2(a.x, a.y));
    r.h[1] = __float22bfloat162_rn(make_float2(a.z, a.w));
    r.h[2] = __float22bfloat162_rn(make_float2(b.x, b.y));
    r.h[3] = __float22bfloat162_rn(make_float2(b.z, b.w));
    return r.u;
}

// K0: h = concat(encsumm, enc) converted to bf16, contiguous per batch
__global__ void k0_stageh(const float* __restrict__ encsumm, const float* __restrict__ enc,
                          float* __restrict__ ws)
{
    int b = blockIdx.x;
    int c = threadIdx.x * 4;                       // 0..1020
    const float* src = (c < DIMK) ? (encsumm + b*DIMK + c) : (enc + b*DIMK + (c - DIMK));
    float4 v = *(const float4*)src;
    union { ushort4 u; __hip_bfloat162 h[2]; } o;
    o.h[0] = __float22bfloat162_rn(make_float2(v.x, v.y));
    o.h[1] = __float22bfloat162_rn(make_float2(v.z, v.w));
    *(ushort4*)((unsigned short*)(ws + WS_H) + b*1024 + c) = o.u;
}

// K1: per (b,m) block — scores + online-softmax weighted sum, memencs read ONCE
__global__ __launch_bounds__(256) void k1_mem(
    const float* __restrict__ enc, const float* __restrict__ embsumm,
    const float* __restrict__ memencs, const float* __restrict__ memembsumm,
    const float* __restrict__ memmask, float* __restrict__ ws)
{
    int blk = blockIdx.x;
    int b = blk >> 5, m = blk & 31;
    int tid = threadIdx.x, wid = tid >> 6, lane = tid & 63;
    int c0 = lane * 4, c1 = c0 + 256;
    const float* encb = enc + b * DIMK;
    const float* embb = embsumm + b * DIMK;
    float4 qe0 = *(const float4*)(encb + c0);
    float4 qe1 = *(const float4*)(encb + c1);
    float4 qm0 = *(const float4*)(embb + c0);
    float4 qm1 = *(const float4*)(embb + c1);
    const float* meb = memencs    + (long)(b*MM + m) * ZZ * DIMK;
    const float* mmb = memembsumm + (long)(b*MM + m) * ZZ * DIMK;
    const float* mkb = memmask    + (long)(b*MM + m) * ZZ;
    float* w_ws = ws + WS_W + b*MZV + m*ZZ;

    float lmax = -3.0e38f, lsum = 0.f;
    float4 a0 = make_float4(0.f,0.f,0.f,0.f), a1 = make_float4(0.f,0.f,0.f,0.f);

    for (int z = wid; z < ZZ; z += 4) {
        const float* mer = meb + z*DIMK;
        const float* mmr = mmb + z*DIMK;
        float4 e0 = *(const float4*)(mer + c0);
        float4 e1 = *(const float4*)(mer + c1);
        float4 s0 = *(const float4*)(mmr + c0);
        float4 s1 = *(const float4*)(mmr + c1);
        float d = e0.x*qe0.x + e0.y*qe0.y + e0.z*qe0.z + e0.w*qe0.w
                + e1.x*qe1.x + e1.y*qe1.y + e1.z*qe1.z + e1.w*qe1.w
                + s0.x*qm0.x + s0.y*qm0.y + s0.z*qm0.z + s0.w*qm0.w
                + s1.x*qm1.x + s1.y*qm1.y + s1.z*qm1.z + s1.w*qm1.w;
        #pragma unroll
        for (int off = 32; off; off >>= 1) d += __shfl_xor(d, off);
        d += logf(mkb[z]);                 // mask=1 -> +0; mask=0 -> -inf
        if (lane == 0) w_ws[z] = d;
        float nm = fmaxf(lmax, d);
        float sc = __expf(lmax - nm);
        float e  = __expf(d - nm);
        lsum = lsum * sc + e;
        a0.x = a0.x*sc + e*e0.x; a0.y = a0.y*sc + e*e0.y;
        a0.z = a0.z*sc + e*e0.z; a0.w = a0.w*sc + e*e0.w;
        a1.x = a1.x*sc + e*e1.x; a1.y = a1.y*sc + e*e1.y;
        a1.z = a1.z*sc + e*e1.z; a1.w = a1.w*sc + e*e1.w;
        lmax = nm;
    }

    __shared__ float sacc[4][DIMK];
    __shared__ float sst[4][2];
    *(float4*)&sacc[wid][c0] = a0;
    *(float4*)&sacc[wid][c1] = a1;
    if (lane == 0) { sst[wid][0] = lmax; sst[wid][1] = lsum; }
    __syncthreads();
    float bm = fmaxf(fmaxf(sst[0][0], sst[1][0]), fmaxf(sst[2][0], sst[3][0]));
    float sc0 = __expf(sst[0][0]-bm), sc1 = __expf(sst[1][0]-bm);
    float sc2 = __expf(sst[2][0]-bm), sc3 = __expf(sst[3][0]-bm);
    float bs = sst[0][1]*sc0 + sst[1][1]*sc1 + sst[2][1]*sc2 + sst[3][1]*sc3;
    int d0 = tid * 2;
    float2 v0 = *(float2*)&sacc[0][d0];
    float2 v1 = *(float2*)&sacc[1][d0];
    float2 v2 = *(float2*)&sacc[2][d0];
    float2 v3 = *(float2*)&sacc[3][d0];
    float p0 = v0.x*sc0 + v1.x*sc1 + v2.x*sc2 + v3.x*sc3;
    float p1 = v0.y*sc0 + v1.y*sc1 + v2.y*sc2 + v3.y*sc3;
    float* pv = ws + WS_PVEC + (long)(b*MM+m)*DIMK + d0;
    pv[0] = p0; pv[1] = p1;
    if (tid == 0) { float* ls = ws + WS_LSTAT + (b*MM+m)*2; ls[0] = bm; ls[1] = bs; }
}

// K2: combine the 32 m-partials per b -> mem_enc_summ (output 1) + global (max,sum)
__global__ __launch_bounds__(256) void k2_comb(float* __restrict__ out, float* __restrict__ ws)
{
    int b = blockIdx.x, tid = threadIdx.x;
    const float* ls = ws + WS_LSTAT + b*MM*2;
    float gm = -3.0e38f;
    #pragma unroll
    for (int m = 0; m < MM; m++) gm = fmaxf(gm, ls[m*2]);
    float gs = 0.f;
    #pragma unroll
    for (int m = 0; m < MM; m++) gs += ls[m*2+1] * __expf(ls[m*2] - gm);
    if (tid == 0) { ws[WS_GSTATW + b*2] = gm; ws[WS_GSTATW + b*2 + 1] = gs; }
    float inv = 1.0f / gs;
    int d0 = tid * 2;
    float p0 = 0.f, p1 = 0.f;
    for (int m = 0; m < MM; m++) {
        float sc = __expf(ls[m*2] - gm);
        const float* pv = ws + WS_PVEC + (long)(b*MM+m)*DIMK + d0;
        p0 += pv[0]*sc; p1 += pv[1]*sc;
    }
    out[(long)NB*VOC + b*DIMK + d0]     = p0 * inv;
    out[(long)NB*VOC + b*DIMK + d0 + 1] = p1 * inv;
}

// K3: mixer gates
__global__ void k3_mix(const float* __restrict__ encsumm, const float* __restrict__ enc,
                       const float* __restrict__ W_mix, const float* __restrict__ b_mix,
                       float* __restrict__ ws)
{
    int b = blockIdx.x, l = threadIdx.x;
    float d0 = 0.f, d1 = 0.f;
    #pragma unroll
    for (int p = 0; p < 4; p++) {
        int cc = l*4 + p*256;
        float4 h4 = (cc < 512) ? *(const float4*)(encsumm + b*DIMK + cc)
                               : *(const float4*)(enc + b*DIMK + cc - 512);
        float4 w0 = *(const float4*)(W_mix + cc);
        float4 w1 = *(const float4*)(W_mix + 1024 + cc);
        d0 += h4.x*w0.x + h4.y*w0.y + h4.z*w0.z + h4.w*w0.w;
        d1 += h4.x*w1.x + h4.y*w1.y + h4.z*w1.z + h4.w*w1.w;
    }
    #pragma unroll
    for (int off = 32; off; off >>= 1) { d0 += __shfl_xor(d0, off); d1 += __shfl_xor(d1, off); }
    if (l == 0) {
        d0 += b_mix[0]; d1 += b_mix[1];
        float mx = fmaxf(d0, d1);
        float e0 = __expf(d0-mx), e1 = __expf(d1-mx);
        float s = e0 + e1;
        ws[WS_MIX + b*2] = e0/s; ws[WS_MIX + b*2 + 1] = e1/s;
    }
}

// K4 v7 (MFMA + 1-barrier pipeline): block = 64 v x 32 b, 4 waves.
// Chunk = 64 k. Double-buffered LDS (B: 2x8KB bf16 swizzled granules,
// A: 2x4KB). Per iter: compute buf[c] -> cvt+ds_write buf[c+1] (waits the
// loads issued one iter ago) -> issue global loads for c+2 -> ONE barrier.
// Staging live regs = 4 float4 + 1 ushort8 = 20 VGPR (spill-safe).
__global__ __launch_bounds__(256) void k4_gemm(
    const unsigned short* __restrict__ hbf,
    const float* __restrict__ W_out, const float* __restrict__ b_out,
    const float* __restrict__ unk, float* __restrict__ logits)
{
    __shared__ __align__(16) unsigned short b_lds[2][8*64*8];   // 2 x 8 KB
    __shared__ __align__(16) unsigned short a_lds[2][8*32*8];   // 2 x 4 KB
    int tid = threadIdx.x, wid = tid >> 6, lane = tid & 63;
    int vt = blockIdx.x * 64;

    // W staging: thread owns 16 contiguous floats (64B) of one W row per chunk
    int r = tid >> 2, q = tid & 3;
    long grow = min(vt + r, VOC - 1);
    const float* wbase = W_out + grow * 1024 + q * 16;
    // A staging: thread owns 1 granule (8 bf16) per chunk
    int ar = tid >> 3, ag = tid & 7;
    const unsigned short* abase = hbf + ar * 1024 + ag * 8;

    int lg = lane >> 4, ln = lane & 15;
    int vrow = wid*16 + ln;

    f32x4 acc0 = {0.f,0.f,0.f,0.f};
    f32x4 acc1 = {0.f,0.f,0.f,0.f};
    float4 f0, f1, f2, f3; ushort8 av;

    int g0 = 2*q, g1 = 2*q + 1;
    int bw0 = (g0*64 + (r ^ ((g0 & 3) << 2))) * 8;
    int bw1 = (g1*64 + (r ^ ((g1 & 3) << 2))) * 8;
    int aw  = (ag*32 + (ar ^ ag)) * 8;

#define LOADC(c) do { const float* wp = wbase + (c)*64;              \
        f0 = *(const float4*)(wp);      f1 = *(const float4*)(wp+4); \
        f2 = *(const float4*)(wp+8);    f3 = *(const float4*)(wp+12);\
        av = *(const ushort8*)(abase + (c)*64); } while (0)
#define WRITEC(buf) do {                                \
        *(ushort8*)&b_lds[buf][bw0] = cvt8(f0, f1);     \
        *(ushort8*)&b_lds[buf][bw1] = cvt8(f2, f3);     \
        *(ushort8*)&a_lds[buf][aw]  = av; } while (0)

    LOADC(0); WRITEC(0);
    LOADC(1);
    __syncthreads();

    #pragma unroll 2
    for (int c = 0; c < 16; ++c) {
        int buf = c & 1;
        #pragma unroll
        for (int s = 0; s < 2; ++s) {
            int g = s*4 + lg;
            short8 bfrag = *(const short8*)&b_lds[buf][(g*64 + (vrow ^ ((g & 3) << 2)))*8];
            short8 a0 = *(const short8*)&a_lds[buf][(g*32 + (ln ^ g))*8];
            short8 a1 = *(const short8*)&a_lds[buf][(g*32 + ((ln + 16) ^ g))*8];
            acc0 = __builtin_amdgcn_mfma_f32_16x16x32_bf16(a0, bfrag, acc0, 0, 0, 0);
            acc1 = __builtin_amdgcn_mfma_f32_16x16x32_bf16(a1, bfrag, acc1, 0, 0, 0);
        }
        if (c < 15) {
            WRITEC(buf ^ 1);            // waits (compiler vmcnt) on loads for c+1
            if (c < 14) LOADC(c + 2);   // in flight across barrier + next compute
        }
        __syncthreads();
    }
#undef LOADC
#undef WRITEC

    // epilogue: C/D layout col=lane&15, row=(lane>>4)*4+reg  (m89-verified)
    int v = vt + vrow;
    if (v < VOC) {
        float bias = b_out[v] + logf(unk[v]);
        #pragma unroll
        for (int rr = 0; rr < 4; ++rr) {
            int m = lg*4 + rr;
            logits[(long)m*VOC + v]        = acc0[rr] + bias;
            logits[(long)(m+16)*VOC + v]   = acc1[rr] + bias;
        }
    }
}

// K5: gen softmax stats, 32 chunks per b
__global__ __launch_bounds__(256) void k5_gstat(const float* __restrict__ logits, float* __restrict__ ws)
{
    int chunk = blockIdx.x, b = blockIdx.y, tid = threadIdx.x;
    const int CH = (VOC + 31) / 32;
    int v0 = chunk * CH;
    int v1 = min(VOC, v0 + CH);
    float m = -3.0e38f, s = 0.f;
    for (int v = v0 + tid; v < v1; v += 256) {
        float x = logits[(long)b*VOC + v];
        float nm = fmaxf(m, x);
        s = s*__expf(m - nm) + __expf(x - nm);
        m = nm;
    }
    #pragma unroll
    for (int off = 32; off; off >>= 1) {
        float om = __shfl_xor(m, off), os = __shfl_xor(s, off);
        float nm = fmaxf(m, om);
        s = s*__expf(m - nm) + os*__expf(om - nm);
        m = nm;
    }
    __shared__ float sm[4], ssum[4];
    int wid = tid >> 6, lane = tid & 63;
    if (lane == 0) { sm[wid] = m; ssum[wid] = s; }
    __syncthreads();
    if (tid == 0) {
        float gm = fmaxf(fmaxf(sm[0], sm[1]), fmaxf(sm[2], sm[3]));
        float gs = ssum[0]*__expf(sm[0]-gm) + ssum[1]*__expf(sm[1]-gm)
                 + ssum[2]*__expf(sm[2]-gm) + ssum[3]*__expf(sm[3]-gm);
        ws[WS_GPART + (b*32 + chunk)*2]     = gm;
        ws[WS_GPART + (b*32 + chunk)*2 + 1] = gs;
    }
}

// K6: probs = mix0 * softmax(logits), in place; merges the 32 chunk partials inline
__global__ __launch_bounds__(256) void k6_final(float* __restrict__ probs, const float* __restrict__ ws)
{
    int v = blockIdx.x*256 + threadIdx.x;
    int b = blockIdx.y;
    float gm = -3.0e38f;
    #pragma unroll
    for (int i = 0; i < 32; ++i) gm = fmaxf(gm, ws[WS_GPART + (b*32+i)*2]);
    float gs = 0.f;
    #pragma unroll
    for (int i = 0; i < 32; ++i)
        gs += ws[WS_GPART + (b*32+i)*2 + 1] * __expf(ws[WS_GPART + (b*32+i)*2] - gm);
    if (v >= VOC) return;
    float mix0 = ws[WS_MIX + b*2];
    long idx = (long)b*VOC + v;
    probs[idx] = mix0 * __expf(probs[idx] - gm) / gs;
}

// K7: copy-branch scatter: probs[b, tok] += mix1*alpha
__global__ __launch_bounds__(256) void k7_scatter(const int* __restrict__ memids,
                                                  const float* __restrict__ ws,
                                                  float* __restrict__ probs)
{
    int idx = blockIdx.x*256 + threadIdx.x;   // NB*MZV = 65536
    int b = idx >> 11, mz = idx & 2047;
    float gm = ws[WS_GSTATW + b*2], gs = ws[WS_GSTATW + b*2 + 1];
    float mix1 = ws[WS_MIX + b*2 + 1];
    float alpha = __expf(ws[WS_W + b*MZV + mz] - gm) / gs;
    int tok = memids[b*MZV + mz];
    atomicAdd(&probs[(long)b*VOC + tok], mix1 * alpha);
}

extern "C" void kernel_launch(void* const* d_in, const int* in_sizes, int n_in,
                              void* d_out, int out_size, void* d_ws, size_t ws_size,
                              hipStream_t stream)
{
    const float* enc        = (const float*)d_in[0];
    const float* encsumm    = (const float*)d_in[1];
    const float* embsumm    = (const float*)d_in[2];
    const float* memencs    = (const float*)d_in[3];
    // d_in[4] = memencsumm: provably unused (zeros in both concat middles)
    const float* memembsumm = (const float*)d_in[5];
    const float* memmask    = (const float*)d_in[6];
    const int*   memids     = (const int*)d_in[7];
    const float* W_out      = (const float*)d_in[8];
    const float* b_out      = (const float*)d_in[9];
    const float* W_mix      = (const float*)d_in[10];
    const float* b_mix      = (const float*)d_in[11];
    const float* unk        = (const float*)d_in[12];
    float* out = (float*)d_out;
    float* ws  = (float*)d_ws;

    hipLaunchKernelGGL(k0_stageh, dim3(NB), dim3(256), 0, stream, encsumm, enc, ws);
    hipLaunchKernelGGL(k1_mem, dim3(NB*MM), dim3(256), 0, stream,
                       enc, embsumm, memencs, memembsumm, memmask, ws);
    hipLaunchKernelGGL(k2_comb, dim3(NB), dim3(256), 0, stream, out, ws);
    hipLaunchKernelGGL(k3_mix, dim3(NB), dim3(64), 0, stream, encsumm, enc, W_mix, b_mix, ws);
    hipLaunchKernelGGL(k4_gemm, dim3((VOC + 63)/64), dim3(256), 0, stream,
                       (const unsigned short*)(ws + WS_H), W_out, b_out, unk, out);
    hipLaunchKernelGGL(k5_gstat, dim3(32, NB), dim3(256), 0, stream, out, ws);
    hipLaunchKernelGGL(k6_final, dim3((VOC + 255)/256, NB), dim3(256), 0, stream, out, ws);
    hipLaunchKernelGGL(k7_scatter, dim3(NB*MZV/256), dim3(256), 0, stream, memids, ws, out);
}